// Round 8
// baseline (126.093 us; speedup 1.0000x reference)
//
#include <hip/hip_runtime.h>
#include <stdint.h>

using bf16   = __bf16;
using bf16x8 = __bf16 __attribute__((ext_vector_type(8)));
using bf16x4 = __bf16 __attribute__((ext_vector_type(4)));
using f32x4  = float  __attribute__((ext_vector_type(4)));
using f32x16 = float  __attribute__((ext_vector_type(16)));
using u32x4  = uint32_t __attribute__((ext_vector_type(4)));

#define DM 1024
#define T_ 2048
#define NH 16

__device__ __forceinline__ void gl_lds16(const void* g, void* l) {
  __builtin_amdgcn_global_load_lds(
      (__attribute__((address_space(1))) void*)g,
      (__attribute__((address_space(3))) void*)l, 16, 0, 0);
}

__device__ __forceinline__ f32x4 mfma16(bf16x8 a, bf16x8 b, f32x4 c) {
  return __builtin_amdgcn_mfma_f32_16x16x32_bf16(a, b, c, 0, 0, 0);
}
__device__ __forceinline__ f32x16 mfma32(bf16x8 a, bf16x8 b, f32x16 c) {
  return __builtin_amdgcn_mfma_f32_32x32x16_bf16(a, b, c, 0, 0, 0);
}
__device__ __forceinline__ uint32_t cvtpk(float lo, float hi) {
  uint32_t r;
  asm volatile("v_cvt_pk_bf16_f32 %0, %1, %2" : "=v"(r) : "v"(lo), "v"(hi));
  return r;
}

// ---------------- cast x (fp32 -> bf16), vectorized ----------------
__global__ __launch_bounds__(256)
void k_cast_x(const float* __restrict__ x, bf16* __restrict__ xb) {
  const size_t i = (size_t)blockIdx.x * 256 + threadIdx.x;
  const float4 a = *(const float4*)(x + i * 8);
  const float4 c = *(const float4*)(x + i * 8 + 4);
  bf16x8 v;
  v[0] = (bf16)a.x; v[1] = (bf16)a.y; v[2] = (bf16)a.z; v[3] = (bf16)a.w;
  v[4] = (bf16)c.x; v[5] = (bf16)c.y; v[6] = (bf16)c.z; v[7] = (bf16)c.w;
  *(bf16x8*)(xb + i * 8) = v;
}

// ------- fused weight transpose-cast: 4 weights in one launch (z selects) -------
__global__ __launch_bounds__(256)
void k_transpose_w4(const float* __restrict__ w0, const float* __restrict__ w1,
                    const float* __restrict__ w2, const float* __restrict__ w3,
                    bf16* __restrict__ wtq, bf16* __restrict__ wto) {
  const int z = blockIdx.z;
  const float* w = (z == 0) ? w0 : (z == 1) ? w1 : (z == 2) ? w2 : w3;
  bf16* wt = (z < 3) ? (wtq + (size_t)z * 1024 * 1024) : wto;
  // fold 1/sqrt(64) * log2(e) into wq so attn softmax runs in exp2 domain
  const float scale = (z == 0) ? 0.125f * 1.44269504f : 1.0f;
  __shared__ float tile[64][68];
  const int tx = threadIdx.x & 15;
  const int ty = threadIdx.x >> 4;
  const int k0 = blockIdx.y * 64, n0 = blockIdx.x * 64;
#pragma unroll
  for (int j = 0; j < 4; ++j) {
    const int r = ty + 16 * j;
    const float4 v = *(const float4*)(w + (size_t)(k0 + r) * DM + n0 + tx * 4);
    tile[r][tx * 4 + 0] = v.x; tile[r][tx * 4 + 1] = v.y;
    tile[r][tx * 4 + 2] = v.z; tile[r][tx * 4 + 3] = v.w;
  }
  __syncthreads();
#pragma unroll
  for (int j = 0; j < 4; ++j) {
    const int r = ty + 16 * j;
    bf16x4 o;
    o[0] = (bf16)(tile[tx * 4 + 0][r] * scale);
    o[1] = (bf16)(tile[tx * 4 + 1][r] * scale);
    o[2] = (bf16)(tile[tx * 4 + 2][r] * scale);
    o[3] = (bf16)(tile[tx * 4 + 3][r] * scale);
    *(bf16x4*)(wt + (size_t)(n0 + r) * DM + k0 + tx * 4) = o;
  }
}

// ---------------- GEMM: C[m][n] = sum_k A[m][k]*BT[n][k] ----------------
// MODE 0 (BN=128): A=xb, BT=[3072][1024] -> Q,K as [B,H,T,64]; V transposed [B,H,64,T]
// MODE 1 (BN=64):  A=attn_out, BT=woT -> Cout fp32 (grid 16x32 = 2 blocks/CU)
template<int MODE>
__global__ __launch_bounds__(256)
void k_gemm(const bf16* __restrict__ A, const bf16* __restrict__ BT,
            bf16* __restrict__ Qg, bf16* __restrict__ Kg, bf16* __restrict__ Vt,
            float* __restrict__ Cout) {
  constexpr int BN = (MODE == 0) ? 128 : 64;
  constexpr int NTW = BN / 32;               // n-subtiles per wave (4 or 2)
  __shared__ __align__(16) bf16 Ash[128 * 32];
  __shared__ __align__(16) bf16 Bsh[BN * 32];
  const int tn = blockIdx.x, tm = blockIdx.y;
  const int lane = threadIdx.x & 63, w = threadIdx.x >> 6;
  const int wm = w >> 1, wn = w & 1;
  const int r16 = lane & 15, g = lane >> 4;
  f32x4 acc[4][NTW] = {};
  const bf16* Arow = A + (size_t)tm * 128 * DM;
  const bf16* Brow = BT + (size_t)tn * BN * DM;
  for (int k0 = 0; k0 < DM; k0 += 32) {
#pragma unroll
    for (int t = 0; t < 2; ++t) {
      const int q = t * 256 + w * 64 + lane;
      gl_lds16(Arow + (size_t)(q >> 2) * DM + k0 + (q & 3) * 8, Ash + (t * 256 + w * 64) * 8);
    }
#pragma unroll
    for (int t = 0; t < BN / 64; ++t) {
      const int q = t * 256 + w * 64 + lane;
      gl_lds16(Brow + (size_t)(q >> 2) * DM + k0 + (q & 3) * 8, Bsh + (t * 256 + w * 64) * 8);
    }
    __syncthreads();
    bf16x8 af[4], bfr[NTW];
#pragma unroll
    for (int mt = 0; mt < 4; ++mt)
      af[mt] = *(const bf16x8*)(Ash + (wm * 64 + mt * 16 + r16) * 32 + g * 8);
#pragma unroll
    for (int nt = 0; nt < NTW; ++nt)
      bfr[nt] = *(const bf16x8*)(Bsh + (wn * (BN / 2) + nt * 16 + r16) * 32 + g * 8);
#pragma unroll
    for (int mt = 0; mt < 4; ++mt)
#pragma unroll
      for (int nt = 0; nt < NTW; ++nt)
        acc[mt][nt] = mfma16(af[mt], bfr[nt], acc[mt][nt]);
    __syncthreads();
  }
  // epilogue; C layout: col = lane&15, row = (lane>>4)*4 + r
#pragma unroll
  for (int mt = 0; mt < 4; ++mt) {
#pragma unroll
    for (int nt = 0; nt < NTW; ++nt) {
      const int ncol = tn * BN + wn * (BN / 2) + nt * 16 + r16;
      const int m0 = tm * 128 + wm * 64 + mt * 16 + g * 4;   // multiple of 4
      if (MODE == 0) {
        const int which = ncol >> 10, nl = ncol & 1023;
        const int h = nl >> 6, d = nl & 63;
        const int b = m0 >> 11, t0 = m0 & 2047;              // no b-crossing in r
        if (which == 2) {
          bf16x4 pv;
#pragma unroll
          for (int r = 0; r < 4; ++r) pv[r] = (bf16)acc[mt][nt][r];
          *(bf16x4*)(Vt + ((size_t)(b * NH + h) * 64 + d) * T_ + t0) = pv;
        } else {
          bf16* dst = (which == 0) ? Qg : Kg;
#pragma unroll
          for (int r = 0; r < 4; ++r)
            dst[(((size_t)(b * NH + h) * T_ + t0 + r) << 6) + d] = (bf16)acc[mt][nt][r];
        }
      } else {
#pragma unroll
        for (int r = 0; r < 4; ++r)
          Cout[(size_t)(m0 + r) * DM + ncol] = acc[mt][nt][r];
      }
    }
  }
}

// ---------------- flash attention: 32x32 MFMA, P in-register ----------------
// grid (qt=16, bh=32), 256 thr = 4 waves x 32 q-rows = 128 q-rows/block.
// S^T = mfma32(K, Q): q = lane&31, key-offset = (r&3)+8*(r>>2)+4*(lane>>5).
// P -> PV A-fragment entirely in registers: per k-step 4 cvt_pk_bf16 +
// 2 v_permlane32_swap (own group keeps j0-3, partner supplies j4-7).
// K/V double-buffered via global_load_lds w/ pre-swizzled source; m=0 softmax.
__global__ __launch_bounds__(256)
void k_attn(const bf16* __restrict__ Qg, const bf16* __restrict__ Kg,
            const bf16* __restrict__ Vtr, bf16* __restrict__ Ao) {
  __shared__ __align__(16) bf16 Ksh[2][64 * 64];
  __shared__ __align__(16) bf16 Vsh[2][64 * 64];
  const int qt = blockIdx.x, bh = blockIdx.y;
  const int lane = threadIdx.x & 63, w = threadIdx.x >> 6;   // 4 waves
  const int l31 = lane & 31, hi = lane >> 5;
  const bf16* Qb = Qg + (size_t)bh * T_ * 64;
  const bf16* Kb = Kg + (size_t)bh * T_ * 64;
  const bf16* Vb = Vtr + (size_t)bh * 64 * T_;
  const int q0 = qt * 128 + w * 32;
  // Q B-fragments: lane holds q = q0+l31, d = s*16 + hi*8 + j
  bf16x8 qb[4];
#pragma unroll
  for (int s = 0; s < 4; ++s)
    qb[s] = *(const bf16x8*)(Qb + (size_t)(q0 + l31) * 64 + s * 16 + hi * 8);
  f32x16 o0 = {}, o1 = {};
  float llocal = 0.f;
  const int swz31 = (l31 & 7) << 4;
  const int srow = lane >> 3;
  const int schunk = (lane & 7) ^ srow;  // pre-swizzled source chunk

  auto stage = [&](bf16* kbuf, bf16* vbuf, int kt0) {
#pragma unroll
    for (int j = 0; j < 2; ++j) {
      const int idx = w * 2 + j;
      const int row = idx * 8 + srow;
      gl_lds16(Kb + (size_t)(kt0 + row) * 64 + schunk * 8, kbuf + idx * 512);
      gl_lds16(Vb + (size_t)row * T_ + kt0 + schunk * 8, vbuf + idx * 512);
    }
  };

  stage(Ksh[0], Vsh[0], 0);
  __syncthreads();
  constexpr int NT = T_ / 64;
  for (int kt = 0; kt < NT; ++kt) {
    const int cur = kt & 1;
    if (kt + 1 < NT) stage(Ksh[cur ^ 1], Vsh[cur ^ 1], (kt + 1) * 64);
    const char* Kc = (const char*)Ksh[cur];
    const char* Vc = (const char*)Vsh[cur];
    // QK^T: st0 = keys 0-31, st1 = keys 32-63 (S^T: q = l31)
    f32x16 st0 = {}, st1 = {};
    __builtin_amdgcn_s_setprio(1);
#pragma unroll
    for (int s = 0; s < 4; ++s) {
      const int cb = (s * 32 + hi * 16) ^ swz31;
      const bf16x8 k0 = *(const bf16x8*)(Kc + l31 * 128 + cb);
      const bf16x8 k1 = *(const bf16x8*)(Kc + (32 + l31) * 128 + cb);
      st0 = mfma32(k0, qb[s], st0);
      st1 = mfma32(k1, qb[s], st1);
    }
    __builtin_amdgcn_s_setprio(0);
    // softmax-lite: p = 2^s in place, accumulate per-lane denom
#pragma unroll
    for (int r = 0; r < 16; ++r) {
      st0[r] = __builtin_amdgcn_exp2f(st0[r]); llocal += st0[r];
    }
#pragma unroll
    for (int r = 0; r < 16; ++r) {
      st1[r] = __builtin_amdgcn_exp2f(st1[r]); llocal += st1[r];
    }
    // PV: per k-step s build P A-frag in regs (cvt_pk + permlane32_swap), then 2 mfma
    __builtin_amdgcn_s_setprio(1);
#pragma unroll
    for (int s = 0; s < 4; ++s) {
      const f32x16& sv = (s < 2) ? st0 : st1;
      const int si = (s & 1) * 8;
      uint32_t a0 = cvtpk(sv[si + 0], sv[si + 1]);
      uint32_t a1 = cvtpk(sv[si + 2], sv[si + 3]);
      uint32_t b0 = cvtpk(sv[si + 4], sv[si + 5]);
      uint32_t b1 = cvtpk(sv[si + 6], sv[si + 7]);
      asm volatile("v_permlane32_swap_b32 %0, %1" : "+v"(a0), "+v"(b0));
      asm volatile("v_permlane32_swap_b32 %0, %1" : "+v"(a1), "+v"(b1));
      u32x4 fr; fr[0] = a0; fr[1] = a1; fr[2] = b0; fr[3] = b1;
      const bf16x8 pas = __builtin_bit_cast(bf16x8, fr);
      const int cb = (s * 32 + hi * 16) ^ swz31;
      const bf16x8 v0 = *(const bf16x8*)(Vc + l31 * 128 + cb);
      const bf16x8 v1 = *(const bf16x8*)(Vc + (32 + l31) * 128 + cb);
      o0 = mfma32(pas, v0, o0);
      o1 = mfma32(pas, v1, o1);
    }
    __builtin_amdgcn_s_setprio(0);
    __syncthreads();
  }
  // denom: each lane summed its key-offsets for q=l31; hi-pair combine
  llocal += __shfl_xor(llocal, 32);
  const int b = bh >> 4, h = bh & 15;
#pragma unroll
  for (int r = 0; r < 16; ++r) {
    const int qoff = (r & 3) + 8 * (r >> 2) + 4 * hi;
    const float linv = 1.f / __shfl(llocal, qoff);
    const size_t base = ((size_t)(b * T_ + q0 + qoff)) * DM + h * 64 + l31;
    Ao[base]      = (bf16)(o0[r] * linv);
    Ao[base + 32] = (bf16)(o1[r] * linv);
  }
}

extern "C" void kernel_launch(void* const* d_in, const int* in_sizes, int n_in,
                              void* d_out, int out_size, void* d_ws, size_t ws_size,
                              hipStream_t stream) {
  const float* x  = (const float*)d_in[0];
  const float* wq = (const float*)d_in[1];
  const float* wk = (const float*)d_in[2];
  const float* wv = (const float*)d_in[3];
  const float* wo = (const float*)d_in[4];
  char* ws = (char*)d_ws;
  const size_t MB = 1024 * 1024;
  bf16* xb   = (bf16*)(ws + 0);        // 8MB: x bf16; reused as attn_out
  bf16* wtq  = (bf16*)(ws + 8 * MB);   // 6MB: [wqT*s; wkT; wvT] = [3072][1024]
  bf16* wto  = (bf16*)(ws + 14 * MB);  // 2MB: woT
  bf16* Qg   = (bf16*)(ws + 16 * MB);  // 8MB [B,H,T,64]
  bf16* Kg   = (bf16*)(ws + 24 * MB);  // 8MB [B,H,T,64]
  bf16* Vtr  = (bf16*)(ws + 32 * MB);  // 8MB [B,H,64,T] (written transposed by GEMM)

  k_cast_x<<<dim3(2048), dim3(256), 0, stream>>>(x, xb);
  k_transpose_w4<<<dim3(16, 16, 4), dim3(256), 0, stream>>>(wq, wk, wv, wo, wtq, wto);
  k_gemm<0><<<dim3(24, 32), dim3(256), 0, stream>>>(xb, wtq, Qg, Kg, Vtr, (float*)nullptr);
  k_attn<<<dim3(16, 32), dim3(256), 0, stream>>>(Qg, Kg, Vtr, xb);
  k_gemm<1><<<dim3(16, 32), dim3(256), 0, stream>>>(xb, wto, (bf16*)nullptr, (bf16*)nullptr,
                                                    (bf16*)nullptr, (float*)d_out);
}

// Round 9
// 122.343 us; speedup vs baseline: 1.0307x; 1.0307x over previous
//
#include <hip/hip_runtime.h>
#include <stdint.h>

using bf16   = __bf16;
using bf16x8 = __bf16 __attribute__((ext_vector_type(8)));
using bf16x4 = __bf16 __attribute__((ext_vector_type(4)));
using f32x4  = float  __attribute__((ext_vector_type(4)));
using f32x16 = float  __attribute__((ext_vector_type(16)));
using u32x4  = uint32_t __attribute__((ext_vector_type(4)));

#define DM 1024
#define T_ 2048
#define NH 16

__device__ __forceinline__ void gl_lds16(const void* g, void* l) {
  __builtin_amdgcn_global_load_lds(
      (__attribute__((address_space(1))) void*)g,
      (__attribute__((address_space(3))) void*)l, 16, 0, 0);
}

__device__ __forceinline__ f32x4 mfma16(bf16x8 a, bf16x8 b, f32x4 c) {
  return __builtin_amdgcn_mfma_f32_16x16x32_bf16(a, b, c, 0, 0, 0);
}
__device__ __forceinline__ f32x16 mfma32(bf16x8 a, bf16x8 b, f32x16 c) {
  return __builtin_amdgcn_mfma_f32_32x32x16_bf16(a, b, c, 0, 0, 0);
}
__device__ __forceinline__ uint32_t cvtpk(float lo, float hi) {
  uint32_t r;
  asm volatile("v_cvt_pk_bf16_f32 %0, %1, %2" : "=v"(r) : "v"(lo), "v"(hi));
  return r;
}

// ---------------- cast x (fp32 -> bf16), vectorized ----------------
__global__ __launch_bounds__(256)
void k_cast_x(const float* __restrict__ x, bf16* __restrict__ xb) {
  const size_t i = (size_t)blockIdx.x * 256 + threadIdx.x;
  const float4 a = *(const float4*)(x + i * 8);
  const float4 c = *(const float4*)(x + i * 8 + 4);
  bf16x8 v;
  v[0] = (bf16)a.x; v[1] = (bf16)a.y; v[2] = (bf16)a.z; v[3] = (bf16)a.w;
  v[4] = (bf16)c.x; v[5] = (bf16)c.y; v[6] = (bf16)c.z; v[7] = (bf16)c.w;
  *(bf16x8*)(xb + i * 8) = v;
}

// ------- fused weight transpose-cast: 4 weights in one launch (z selects) -------
__global__ __launch_bounds__(256)
void k_transpose_w4(const float* __restrict__ w0, const float* __restrict__ w1,
                    const float* __restrict__ w2, const float* __restrict__ w3,
                    bf16* __restrict__ wtq, bf16* __restrict__ wto) {
  const int z = blockIdx.z;
  const float* w = (z == 0) ? w0 : (z == 1) ? w1 : (z == 2) ? w2 : w3;
  bf16* wt = (z < 3) ? (wtq + (size_t)z * 1024 * 1024) : wto;
  // fold 1/sqrt(64) * log2(e) into wq so attn softmax runs in exp2 domain
  const float scale = (z == 0) ? 0.125f * 1.44269504f : 1.0f;
  __shared__ float tile[64][68];
  const int tx = threadIdx.x & 15;
  const int ty = threadIdx.x >> 4;
  const int k0 = blockIdx.y * 64, n0 = blockIdx.x * 64;
#pragma unroll
  for (int j = 0; j < 4; ++j) {
    const int r = ty + 16 * j;
    const float4 v = *(const float4*)(w + (size_t)(k0 + r) * DM + n0 + tx * 4);
    tile[r][tx * 4 + 0] = v.x; tile[r][tx * 4 + 1] = v.y;
    tile[r][tx * 4 + 2] = v.z; tile[r][tx * 4 + 3] = v.w;
  }
  __syncthreads();
#pragma unroll
  for (int j = 0; j < 4; ++j) {
    const int r = ty + 16 * j;
    bf16x4 o;
    o[0] = (bf16)(tile[tx * 4 + 0][r] * scale);
    o[1] = (bf16)(tile[tx * 4 + 1][r] * scale);
    o[2] = (bf16)(tile[tx * 4 + 2][r] * scale);
    o[3] = (bf16)(tile[tx * 4 + 3][r] * scale);
    *(bf16x4*)(wt + (size_t)(n0 + r) * DM + k0 + tx * 4) = o;
  }
}

// ---------------- GEMM: C[m][n] = sum_k A[m][k]*BT[n][k] ----------------
// MODE 0 (BN=128): A=xb, BT=[3072][1024] -> Q,K as [B,H,T,64]; V transposed [B,H,64,T]
// MODE 1 (BN=64):  A=attn_out, BT=woT -> Cout fp32 (grid 16x32 = 2 blocks/CU)
template<int MODE>
__global__ __launch_bounds__(256)
void k_gemm(const bf16* __restrict__ A, const bf16* __restrict__ BT,
            bf16* __restrict__ Qg, bf16* __restrict__ Kg, bf16* __restrict__ Vt,
            float* __restrict__ Cout) {
  constexpr int BN = (MODE == 0) ? 128 : 64;
  constexpr int NTW = BN / 32;               // n-subtiles per wave (4 or 2)
  __shared__ __align__(16) bf16 Ash[128 * 32];
  __shared__ __align__(16) bf16 Bsh[BN * 32];
  const int tn = blockIdx.x, tm = blockIdx.y;
  const int lane = threadIdx.x & 63, w = threadIdx.x >> 6;
  const int wm = w >> 1, wn = w & 1;
  const int r16 = lane & 15, g = lane >> 4;
  f32x4 acc[4][NTW] = {};
  const bf16* Arow = A + (size_t)tm * 128 * DM;
  const bf16* Brow = BT + (size_t)tn * BN * DM;
  for (int k0 = 0; k0 < DM; k0 += 32) {
#pragma unroll
    for (int t = 0; t < 2; ++t) {
      const int q = t * 256 + w * 64 + lane;
      gl_lds16(Arow + (size_t)(q >> 2) * DM + k0 + (q & 3) * 8, Ash + (t * 256 + w * 64) * 8);
    }
#pragma unroll
    for (int t = 0; t < BN / 64; ++t) {
      const int q = t * 256 + w * 64 + lane;
      gl_lds16(Brow + (size_t)(q >> 2) * DM + k0 + (q & 3) * 8, Bsh + (t * 256 + w * 64) * 8);
    }
    __syncthreads();
    bf16x8 af[4], bfr[NTW];
#pragma unroll
    for (int mt = 0; mt < 4; ++mt)
      af[mt] = *(const bf16x8*)(Ash + (wm * 64 + mt * 16 + r16) * 32 + g * 8);
#pragma unroll
    for (int nt = 0; nt < NTW; ++nt)
      bfr[nt] = *(const bf16x8*)(Bsh + (wn * (BN / 2) + nt * 16 + r16) * 32 + g * 8);
#pragma unroll
    for (int mt = 0; mt < 4; ++mt)
#pragma unroll
      for (int nt = 0; nt < NTW; ++nt)
        acc[mt][nt] = mfma16(af[mt], bfr[nt], acc[mt][nt]);
    __syncthreads();
  }
  // epilogue; C layout: col = lane&15, row = (lane>>4)*4 + r
#pragma unroll
  for (int mt = 0; mt < 4; ++mt) {
#pragma unroll
    for (int nt = 0; nt < NTW; ++nt) {
      const int ncol = tn * BN + wn * (BN / 2) + nt * 16 + r16;
      const int m0 = tm * 128 + wm * 64 + mt * 16 + g * 4;   // multiple of 4
      if (MODE == 0) {
        const int which = ncol >> 10, nl = ncol & 1023;
        const int h = nl >> 6, d = nl & 63;
        const int b = m0 >> 11, t0 = m0 & 2047;              // no b-crossing in r
        if (which == 2) {
          bf16x4 pv;
#pragma unroll
          for (int r = 0; r < 4; ++r) pv[r] = (bf16)acc[mt][nt][r];
          *(bf16x4*)(Vt + ((size_t)(b * NH + h) * 64 + d) * T_ + t0) = pv;
        } else {
          bf16* dst = (which == 0) ? Qg : Kg;
#pragma unroll
          for (int r = 0; r < 4; ++r)
            dst[(((size_t)(b * NH + h) * T_ + t0 + r) << 6) + d] = (bf16)acc[mt][nt][r];
        }
      } else {
#pragma unroll
        for (int r = 0; r < 4; ++r)
          Cout[(size_t)(m0 + r) * DM + ncol] = acc[mt][nt][r];
      }
    }
  }
}

// ---------- flash attention: 32x32 MFMA, in-reg P, split-K over key halves ----------
// grid (qt=16, bh=32), 512 thr = 8 waves: qw = w&3 (q-tile of 32 rows),
// kh = w>>2 (key half: tiles kh*16..kh*16+15). m=0 softmax makes partials
// additive: O and l summed across kh at the end via LDS (aliasing dead Ksh).
// Per-group double-buffered K/V staging, proven stage-top/barrier-bottom skeleton.
__global__ __launch_bounds__(512)
void k_attn(const bf16* __restrict__ Qg, const bf16* __restrict__ Kg,
            const bf16* __restrict__ Vtr, bf16* __restrict__ Ao) {
  __shared__ __align__(16) bf16 Ksh[2][2][64 * 64];   // [kh][dbuf] 32KB
  __shared__ __align__(16) bf16 Vsh[2][2][64 * 64];   // 32KB
  __shared__ float Lsh[4][64];                        // 1KB
  const int qt = blockIdx.x, bh = blockIdx.y;
  const int lane = threadIdx.x & 63, w = threadIdx.x >> 6;
  const int qw = w & 3, kh = w >> 2;
  const int l31 = lane & 31, hi = lane >> 5;
  const bf16* Qb = Qg + (size_t)bh * T_ * 64;
  const bf16* Kb = Kg + (size_t)bh * T_ * 64;
  const bf16* Vb = Vtr + (size_t)bh * 64 * T_;
  const int q0 = qt * 128 + qw * 32;
  // Q B-fragments: lane holds q = q0+l31, d = s*16 + hi*8 + j
  bf16x8 qb[4];
#pragma unroll
  for (int s = 0; s < 4; ++s)
    qb[s] = *(const bf16x8*)(Qb + (size_t)(q0 + l31) * 64 + s * 16 + hi * 8);
  f32x16 o0 = {}, o1 = {};
  float llocal = 0.f;
  const int swz31 = (l31 & 7) << 4;
  const int srow = lane >> 3;
  const int schunk = (lane & 7) ^ srow;  // pre-swizzled source chunk

  // group kh stages its own tile stream (8 K-slabs + 8 V-slabs via 4 waves x 2)
  auto stage = [&](int buf, int ti) {
#pragma unroll
    for (int j = 0; j < 2; ++j) {
      const int idx = qw * 2 + j;
      const int row = idx * 8 + srow;
      gl_lds16(Kb + (size_t)(ti * 64 + row) * 64 + schunk * 8, &Ksh[kh][buf][idx * 512]);
      gl_lds16(Vb + (size_t)row * T_ + ti * 64 + schunk * 8, &Vsh[kh][buf][idx * 512]);
    }
  };

  constexpr int NTH = T_ / 64 / 2;       // 16 tiles per key-half
  stage(0, kh * NTH);
  __syncthreads();
  for (int i = 0; i < NTH; ++i) {
    const int cur = i & 1;
    if (i + 1 < NTH) stage(cur ^ 1, kh * NTH + i + 1);
    const char* Kc = (const char*)Ksh[kh][cur];
    const char* Vc = (const char*)Vsh[kh][cur];
    // QK^T: st0 = keys 0-31 of tile, st1 = keys 32-63 (S^T cols = q = l31)
    f32x16 st0 = {}, st1 = {};
    __builtin_amdgcn_s_setprio(1);
#pragma unroll
    for (int s = 0; s < 4; ++s) {
      const int cb = (s * 32 + hi * 16) ^ swz31;
      const bf16x8 k0 = *(const bf16x8*)(Kc + l31 * 128 + cb);
      const bf16x8 k1 = *(const bf16x8*)(Kc + (32 + l31) * 128 + cb);
      st0 = mfma32(k0, qb[s], st0);
      st1 = mfma32(k1, qb[s], st1);
    }
    __builtin_amdgcn_s_setprio(0);
    // softmax-lite: p = 2^s in place, accumulate per-lane denom
#pragma unroll
    for (int r = 0; r < 16; ++r) {
      st0[r] = __builtin_amdgcn_exp2f(st0[r]); llocal += st0[r];
    }
#pragma unroll
    for (int r = 0; r < 16; ++r) {
      st1[r] = __builtin_amdgcn_exp2f(st1[r]); llocal += st1[r];
    }
    // PV: per k-step s build P A-frag in regs (cvt_pk + permlane32_swap), 2 mfma
    __builtin_amdgcn_s_setprio(1);
#pragma unroll
    for (int s = 0; s < 4; ++s) {
      const f32x16& sv = (s < 2) ? st0 : st1;
      const int si = (s & 1) * 8;
      uint32_t a0 = cvtpk(sv[si + 0], sv[si + 1]);
      uint32_t a1 = cvtpk(sv[si + 2], sv[si + 3]);
      uint32_t b0 = cvtpk(sv[si + 4], sv[si + 5]);
      uint32_t b1 = cvtpk(sv[si + 6], sv[si + 7]);
      asm volatile("v_permlane32_swap_b32 %0, %1" : "+v"(a0), "+v"(b0));
      asm volatile("v_permlane32_swap_b32 %0, %1" : "+v"(a1), "+v"(b1));
      u32x4 fr; fr[0] = a0; fr[1] = a1; fr[2] = b0; fr[3] = b1;
      const bf16x8 pas = __builtin_bit_cast(bf16x8, fr);
      const int cb = (s * 32 + hi * 16) ^ swz31;
      const bf16x8 v0 = *(const bf16x8*)(Vc + l31 * 128 + cb);
      const bf16x8 v1 = *(const bf16x8*)(Vc + (32 + l31) * 128 + cb);
      o0 = mfma32(pas, v0, o0);
      o1 = mfma32(pas, v1, o1);
    }
    __builtin_amdgcn_s_setprio(0);
    __syncthreads();
  }
  // ---- cross-wave combine: kh=1 dumps partials into LDS (K buffers are dead) ----
  float* cb = (float*)&Ksh[0][0][0] + qw * 2048;   // [32][64] f32 per q-tile
  if (kh == 1) {
#pragma unroll
    for (int r = 0; r < 16; ++r) {
      cb[r * 64 + lane]        = o0[r];
      cb[(16 + r) * 64 + lane] = o1[r];
    }
    Lsh[qw][lane] = llocal;
  }
  __syncthreads();
  if (kh == 0) {
    llocal += Lsh[qw][lane];
#pragma unroll
    for (int r = 0; r < 16; ++r) {
      o0[r] += cb[r * 64 + lane];
      o1[r] += cb[(16 + r) * 64 + lane];
    }
    llocal += __shfl_xor(llocal, 32);
    const int b = bh >> 4, h = bh & 15;
#pragma unroll
    for (int r = 0; r < 16; ++r) {
      const int qoff = (r & 3) + 8 * (r >> 2) + 4 * hi;
      const float linv = 1.f / __shfl(llocal, qoff);
      const size_t base = ((size_t)(b * T_ + q0 + qoff)) * DM + h * 64 + l31;
      Ao[base]      = (bf16)(o0[r] * linv);
      Ao[base + 32] = (bf16)(o1[r] * linv);
    }
  }
}

extern "C" void kernel_launch(void* const* d_in, const int* in_sizes, int n_in,
                              void* d_out, int out_size, void* d_ws, size_t ws_size,
                              hipStream_t stream) {
  const float* x  = (const float*)d_in[0];
  const float* wq = (const float*)d_in[1];
  const float* wk = (const float*)d_in[2];
  const float* wv = (const float*)d_in[3];
  const float* wo = (const float*)d_in[4];
  char* ws = (char*)d_ws;
  const size_t MB = 1024 * 1024;
  bf16* xb   = (bf16*)(ws + 0);        // 8MB: x bf16; reused as attn_out
  bf16* wtq  = (bf16*)(ws + 8 * MB);   // 6MB: [wqT*s; wkT; wvT] = [3072][1024]
  bf16* wto  = (bf16*)(ws + 14 * MB);  // 2MB: woT
  bf16* Qg   = (bf16*)(ws + 16 * MB);  // 8MB [B,H,T,64]
  bf16* Kg   = (bf16*)(ws + 24 * MB);  // 8MB [B,H,T,64]
  bf16* Vtr  = (bf16*)(ws + 32 * MB);  // 8MB [B,H,64,T] (written transposed by GEMM)

  k_cast_x<<<dim3(2048), dim3(256), 0, stream>>>(x, xb);
  k_transpose_w4<<<dim3(16, 16, 4), dim3(256), 0, stream>>>(wq, wk, wv, wo, wtq, wto);
  k_gemm<0><<<dim3(24, 32), dim3(256), 0, stream>>>(xb, wtq, Qg, Kg, Vtr, (float*)nullptr);
  k_attn<<<dim3(16, 32), dim3(512), 0, stream>>>(Qg, Kg, Vtr, xb);
  k_gemm<1><<<dim3(16, 32), dim3(256), 0, stream>>>(xb, wto, (bf16*)nullptr, (bf16*)nullptr,
                                                    (bf16*)nullptr, (float*)d_out);
}